// Round 1
// baseline (436.602 us; speedup 1.0000x reference)
//
#include <hip/hip_runtime.h>
#include <math.h>

#define DEV __device__ __forceinline__

constexpr int BATCH = 8;
constexpr int LL    = 4096;   // H*W
constexpr int DM    = 96;     // d_model
constexpr int DI    = 192;    // d_inner
constexpr int KK    = 4;      // scan directions
constexpr int NS    = 16;     // d_state
constexpr int RR    = 6;      // dt_rank
constexpr int NC    = 64;     // chunks per scan
constexpr int CHUNK = 64;     // L / NC
constexpr int SUB   = 32;     // staging sub-block
constexpr int PST   = 40;     // padded proj row stride (6 dt | pad2 | 16 B | 16 C)

DEV float fsilu(float x){ return x / (1.f + __expf(-x)); }
DEV float fsoftplus(float x){ return (x > 15.f) ? x : __logf(1.f + __expf(x)); }

// physical pixel index for direction KD at scan position l  (W == 64 == 2^6)
template<int KD> DEV int pmapT(int l){
  if constexpr (KD == 0) return l;
  else if constexpr (KD == 1) return ((l & 63) << 6) | (l >> 6);
  else if constexpr (KD == 2) return (LL - 1) - l;
  else { int m = (LL - 1) - l; return ((m & 63) << 6) | (m >> 6); }
}

// ---------------------------------------------------------------- in_proj GEMM
// x:(32768,96) @ Wi^T:(96,384) -> xa:(32768,192) [first half], zs=silu [second half]
constexpr int IP_KC = 24;
__global__ __launch_bounds__(256) void k_inproj(
    const float* __restrict__ x, const float* __restrict__ Wi,
    float* __restrict__ xa, float* __restrict__ zs)
{
  __shared__ float xt[96][36];          // [k][p], rows 144B (16B aligned)
  __shared__ float wl[384][IP_KC + 1];  // [j][kk], pad -> conflict-free reads
  const int g0  = blockIdx.x * 32;      // 32 pixels per block
  const int tid = threadIdx.x;
  const int jg  = tid & 31;             // j = jg + 32*i  (i<12)
  const int pg  = tid >> 5;             // p = pg*4 + pp  (pp<4)

  float acc[4][12];
#pragma unroll
  for (int a = 0; a < 4; ++a)
#pragma unroll
    for (int i = 0; i < 12; ++i) acc[a][i] = 0.f;

  for (int idx = tid; idx < 32 * 96; idx += 256){
    int k = idx % 96, p = idx / 96;
    xt[k][p] = x[(size_t)(g0 + p) * 96 + k];
  }
  for (int kc = 0; kc < 96; kc += IP_KC){
    for (int idx = tid; idx < 384 * IP_KC; idx += 256){
      int kk = idx % IP_KC, j = idx / IP_KC;
      wl[j][kk] = Wi[(size_t)j * 96 + kc + kk];
    }
    __syncthreads();
#pragma unroll
    for (int kk = 0; kk < IP_KC; ++kk){
      const float4 xv = *(const float4*)&xt[kc + kk][pg * 4];
      float w[12];
#pragma unroll
      for (int i = 0; i < 12; ++i) w[i] = wl[jg + 32 * i][kk];
#pragma unroll
      for (int i = 0; i < 12; ++i){
        acc[0][i] = __builtin_fmaf(xv.x, w[i], acc[0][i]);
        acc[1][i] = __builtin_fmaf(xv.y, w[i], acc[1][i]);
        acc[2][i] = __builtin_fmaf(xv.z, w[i], acc[2][i]);
        acc[3][i] = __builtin_fmaf(xv.w, w[i], acc[3][i]);
      }
    }
    __syncthreads();
  }
#pragma unroll
  for (int pp = 0; pp < 4; ++pp){
    const int p = g0 + pg * 4 + pp;
#pragma unroll
    for (int i = 0; i < 12; ++i){
      const int j = jg + 32 * i;
      const float v = acc[pp][i];
      if (j < DI) xa[(size_t)p * DI + j] = v;
      else        zs[(size_t)p * DI + (j - DI)] = fsilu(v);
    }
  }
}

// ---------------------------------------------------------------- depthwise 3x3 conv + silu
__global__ __launch_bounds__(256) void k_conv(
    const float* __restrict__ xa, const float* __restrict__ cw,
    const float* __restrict__ cb, float* __restrict__ xc)
{
  const int gid = blockIdx.x * 256 + threadIdx.x;   // (b, p, d4)
  const int d4 = gid % 48;
  const int p  = (gid / 48) & (LL - 1);
  const int b  = gid / (48 * LL);
  const int d0 = d4 * 4;
  const int hh = p >> 6, wp = p & 63;

  float wg0[9], wg1[9], wg2[9], wg3[9];
#pragma unroll
  for (int j = 0; j < 9; ++j){
    wg0[j] = cw[(d0 + 0) * 9 + j];
    wg1[j] = cw[(d0 + 1) * 9 + j];
    wg2[j] = cw[(d0 + 2) * 9 + j];
    wg3[j] = cw[(d0 + 3) * 9 + j];
  }
  float a0 = cb[d0], a1 = cb[d0 + 1], a2 = cb[d0 + 2], a3 = cb[d0 + 3];
  const float* base = xa + (size_t)b * LL * DI + d0;
#pragma unroll
  for (int dy = 0; dy < 3; ++dy){
    const int hy = hh + dy - 1;
    if ((unsigned)hy >= 64u) continue;
#pragma unroll
    for (int dx = 0; dx < 3; ++dx){
      const int wx = wp + dx - 1;
      if ((unsigned)wx >= 64u) continue;
      const float4 v = *(const float4*)(base + (size_t)(hy * 64 + wx) * DI);
      const int j = dy * 3 + dx;
      a0 = __builtin_fmaf(v.x, wg0[j], a0);
      a1 = __builtin_fmaf(v.y, wg1[j], a1);
      a2 = __builtin_fmaf(v.z, wg2[j], a2);
      a3 = __builtin_fmaf(v.w, wg3[j], a3);
    }
  }
  float4 o; o.x = fsilu(a0); o.y = fsilu(a1); o.z = fsilu(a2); o.w = fsilu(a3);
  *(float4*)(xc + ((size_t)b * LL + p) * DI + d0) = o;
}

// ---------------------------------------------------------------- x_proj (4 dirs fused), per physical pixel
// xc:(b,p,192) -> projP:(b,k,p,40)  [0..5]=dt, [8..23]=B, [24..39]=C
constexpr int XP_KC = 32;
__global__ __launch_bounds__(256) void k_xproj(
    const float* __restrict__ xc, const float* __restrict__ Wp, float* __restrict__ projP)
{
  __shared__ float xl[XP_KC][68];    // [kk][p], 272B rows (16B aligned)
  __shared__ float wl[XP_KC][161];   // [kk][c2], pad for banks
  const int b   = blockIdx.x / (LL / 64);
  const int p0  = (blockIdx.x % (LL / 64)) * 64;
  const int tid = threadIdx.x;
  const int cg  = tid & 15;          // c2 = cg + 16*i  (i<10)
  const int pg  = tid >> 4;          // p  = pg*4 + pp

  float acc[4][10];
#pragma unroll
  for (int a = 0; a < 4; ++a)
#pragma unroll
    for (int i = 0; i < 10; ++i) acc[a][i] = 0.f;

  for (int dd0 = 0; dd0 < DI; dd0 += XP_KC){
    __syncthreads();
    for (int idx = tid; idx < 8 * 64; idx += 256){
      int q = idx & 7, p = idx >> 3;
      const float4 v = *(const float4*)&xc[((size_t)b * LL + p0 + p) * DI + dd0 + q * 4];
      xl[q * 4 + 0][p] = v.x; xl[q * 4 + 1][p] = v.y;
      xl[q * 4 + 2][p] = v.z; xl[q * 4 + 3][p] = v.w;
    }
    for (int idx = tid; idx < XP_KC * 160; idx += 256){
      int kk = idx & 31, c2 = idx >> 5;
      int k = c2 / 40, c = c2 % 40;
      wl[kk][c2] = (c < 38) ? Wp[(size_t)(k * 38 + c) * DI + dd0 + kk] : 0.f;
    }
    __syncthreads();
#pragma unroll
    for (int kk = 0; kk < XP_KC; ++kk){
      const float4 xv = *(const float4*)&xl[kk][pg * 4];
      float w[10];
#pragma unroll
      for (int i = 0; i < 10; ++i) w[i] = wl[kk][cg + 16 * i];
#pragma unroll
      for (int i = 0; i < 10; ++i){
        acc[0][i] = __builtin_fmaf(xv.x, w[i], acc[0][i]);
        acc[1][i] = __builtin_fmaf(xv.y, w[i], acc[1][i]);
        acc[2][i] = __builtin_fmaf(xv.z, w[i], acc[2][i]);
        acc[3][i] = __builtin_fmaf(xv.w, w[i], acc[3][i]);
      }
    }
  }
#pragma unroll
  for (int i = 0; i < 10; ++i){
    const int c2 = cg + 16 * i;
    const int k = c2 / 40, c = c2 % 40;
    if (c < 38){
      const int off = c + (c >= 6 ? 2 : 0);
#pragma unroll
      for (int pp = 0; pp < 4; ++pp){
        const int p = p0 + pg * 4 + pp;
        projP[((size_t)(b * KK + k) * LL + p) * PST + off] = acc[pp][i];
      }
    }
  }
}

// ---------------------------------------------------------------- selective scan (chunked, 2-pass)
template<int KD, bool PASS2, bool ACC>
DEV void scan_chunk(int b, int cc,
    const float* __restrict__ projP, const float* __restrict__ xc,
    const float* __restrict__ Wdt, const float* __restrict__ dtb,
    const float* __restrict__ Alog, const float* __restrict__ DsP,
    const float* __restrict__ H0,
    float* __restrict__ Sh, float* __restrict__ Ssum,
    float* __restrict__ yX, float (*pbuf)[PST])
{
  const int d  = threadIdx.x;
  const int kd = KD * DI + d;

  float A[NS];
#pragma unroll
  for (int n = 0; n < NS; ++n) A[n] = -__expf(Alog[(size_t)kd * NS + n]);

  float wdt[RR];
#pragma unroll
  for (int r = 0; r < RR; ++r) wdt[r] = Wdt[kd * RR + r];
  const float bias = dtb[kd];

  float h[NS];
  float dskd = 0.f;
  if constexpr (PASS2){
    const float* h0p = H0 + ((size_t)((b * KK + KD) * NC + cc) * DI + d) * NS;
#pragma unroll
    for (int n = 0; n < NS; ++n) h[n] = h0p[n];
    dskd = DsP[kd];
  } else {
#pragma unroll
    for (int n = 0; n < NS; ++n) h[n] = 0.f;
  }

  float sdl = 0.f;
  const int l0 = cc * CHUNK;
  const float* pbase = projP + (size_t)(b * KK + KD) * LL * PST;
  const float* xbase = xc + (size_t)b * LL * DI;
  float* ybase = PASS2 ? (yX + (size_t)b * LL * DI) : nullptr;

  float u_nx = xbase[(size_t)pmapT<KD>(l0) * DI + d];

  for (int sb = 0; sb < CHUNK; sb += SUB){
    __syncthreads();
    for (int idx = threadIdx.x; idx < SUB * (PST / 4); idx += DI){
      const int s = idx / (PST / 4), c4 = idx % (PST / 4);
      const float4 v = *(const float4*)(pbase + (size_t)pmapT<KD>(l0 + sb + s) * PST + c4 * 4);
      *(float4*)&pbuf[s][c4 * 4] = v;
    }
    __syncthreads();
#pragma unroll 2
    for (int s = 0; s < SUB; ++s){
      const int l = l0 + sb + s;
      const float u = u_nx;
      const int ln = (l + 1 < l0 + CHUNK) ? (l + 1) : l0;   // dummy prefetch at end
      u_nx = xbase[(size_t)pmapT<KD>(ln) * DI + d];

      const float4 dt0 = *(const float4*)&pbuf[s][0];
      const float2 dt1 = *(const float2*)&pbuf[s][4];
      float dr = bias + dt0.x * wdt[0] + dt0.y * wdt[1] + dt0.z * wdt[2]
                      + dt0.w * wdt[3] + dt1.x * wdt[4] + dt1.y * wdt[5];
      const float dl = fsoftplus(dr);
      if constexpr (!PASS2) sdl += dl;
      const float du = dl * u;

      const float4 B0 = *(const float4*)&pbuf[s][8];
      const float4 B1 = *(const float4*)&pbuf[s][12];
      const float4 B2 = *(const float4*)&pbuf[s][16];
      const float4 B3 = *(const float4*)&pbuf[s][20];
      const float Bv[NS] = {B0.x,B0.y,B0.z,B0.w, B1.x,B1.y,B1.z,B1.w,
                            B2.x,B2.y,B2.z,B2.w, B3.x,B3.y,B3.z,B3.w};
      float Cv[NS];
      float y = 0.f;
      if constexpr (PASS2){
        const float4 C0 = *(const float4*)&pbuf[s][24];
        const float4 C1 = *(const float4*)&pbuf[s][28];
        const float4 C2 = *(const float4*)&pbuf[s][32];
        const float4 C3 = *(const float4*)&pbuf[s][36];
        Cv[0]=C0.x; Cv[1]=C0.y; Cv[2]=C0.z; Cv[3]=C0.w;
        Cv[4]=C1.x; Cv[5]=C1.y; Cv[6]=C1.z; Cv[7]=C1.w;
        Cv[8]=C2.x; Cv[9]=C2.y; Cv[10]=C2.z; Cv[11]=C2.w;
        Cv[12]=C3.x; Cv[13]=C3.y; Cv[14]=C3.z; Cv[15]=C3.w;
        y = dskd * u;
      }
#pragma unroll
      for (int n = 0; n < NS; ++n){
        const float e  = __expf(dl * A[n]);
        const float hv = __builtin_fmaf(e, h[n], Bv[n] * du);
        h[n] = hv;
        if constexpr (PASS2) y = __builtin_fmaf(hv, Cv[n], y);
      }
      if constexpr (PASS2){
        float* dst = ybase + (size_t)pmapT<KD>(l) * DI + d;
        if constexpr (ACC) *dst += y; else *dst = y;
      }
    }
  }

  if constexpr (!PASS2){
    float* shp = Sh + ((size_t)((b * KK + KD) * NC + cc) * DI + d) * NS;
#pragma unroll
    for (int n = 0; n < NS; ++n) shp[n] = h[n];
    Ssum[(size_t)((b * KK + KD) * NC + cc) * DI + d] = sdl;
  }
}

__global__ __launch_bounds__(192) void k_pass1(
    const float* __restrict__ projP, const float* __restrict__ xc,
    const float* __restrict__ Wdt, const float* __restrict__ dtb,
    const float* __restrict__ Alog, float* __restrict__ Sh, float* __restrict__ Ssum)
{
  __shared__ float pbuf[SUB][PST];
  const int bid = blockIdx.x;
  const int cc = bid & (NC - 1);
  const int k  = (bid >> 6) & 3;
  const int b  = bid >> 8;
  switch (k){
    case 0: scan_chunk<0,false,false>(b,cc,projP,xc,Wdt,dtb,Alog,nullptr,nullptr,Sh,Ssum,nullptr,pbuf); break;
    case 1: scan_chunk<1,false,false>(b,cc,projP,xc,Wdt,dtb,Alog,nullptr,nullptr,Sh,Ssum,nullptr,pbuf); break;
    case 2: scan_chunk<2,false,false>(b,cc,projP,xc,Wdt,dtb,Alog,nullptr,nullptr,Sh,Ssum,nullptr,pbuf); break;
    default: scan_chunk<3,false,false>(b,cc,projP,xc,Wdt,dtb,Alog,nullptr,nullptr,Sh,Ssum,nullptr,pbuf); break;
  }
}

// chunk-prefix: in-place Sh -> H0 (state BEFORE each chunk)
__global__ __launch_bounds__(256) void k_prefix(
    float* __restrict__ ShH0, const float* __restrict__ Ssum, const float* __restrict__ Alog)
{
  const int gid = blockIdx.x * 256 + threadIdx.x;     // 32*192*16 = 98304
  const int n  = gid & 15;
  const int d  = (gid >> 4) % DI;
  const int bk = gid / (16 * DI);
  const float A = -__expf(Alog[(size_t)((bk & 3) * DI + d) * NS + n]);
  float h0 = 0.f;
  for (int c = 0; c < NC; ++c){
    const size_t ix = ((size_t)(bk * NC + c) * DI + d) * NS + n;
    const float sh = ShH0[ix];
    const float P  = __expf(Ssum[(size_t)(bk * NC + c) * DI + d] * A);
    ShH0[ix] = h0;
    h0 = __builtin_fmaf(P, h0, sh);
  }
}

__global__ __launch_bounds__(192) void k_pass2(
    const float* __restrict__ projP, const float* __restrict__ xc,
    const float* __restrict__ Wdt, const float* __restrict__ dtb,
    const float* __restrict__ Alog, const float* __restrict__ DsP,
    const float* __restrict__ H0, float* __restrict__ yA, float* __restrict__ yB)
{
  __shared__ float pbuf[SUB][PST];
  const int bid = blockIdx.x;
  const int cc   = bid & (NC - 1);
  const int pair = (bid >> 6) & 1;
  const int b    = bid >> 7;
  if (pair == 0){
    scan_chunk<0,true,false>(b,cc,     projP,xc,Wdt,dtb,Alog,DsP,H0,nullptr,nullptr,yA,pbuf);
    __syncthreads();
    scan_chunk<2,true,true >(b,NC-1-cc,projP,xc,Wdt,dtb,Alog,DsP,H0,nullptr,nullptr,yA,pbuf);
  } else {
    scan_chunk<1,true,false>(b,cc,     projP,xc,Wdt,dtb,Alog,DsP,H0,nullptr,nullptr,yB,pbuf);
    __syncthreads();
    scan_chunk<3,true,true >(b,NC-1-cc,projP,xc,Wdt,dtb,Alog,DsP,H0,nullptr,nullptr,yB,pbuf);
  }
}

// ---------------------------------------------------------------- merge + LayerNorm + silu(z) gate
__global__ __launch_bounds__(256) void k_mergeln(
    const float* __restrict__ yA, const float* __restrict__ yB,
    const float* __restrict__ zs, const float* __restrict__ wn,
    const float* __restrict__ bn, float* __restrict__ t)
{
  const int g = blockIdx.x * 4 + (threadIdx.x >> 6);   // global pixel
  const int lane = threadIdx.x & 63;
  const float* ya = yA + (size_t)g * DI;
  const float* yb = yB + (size_t)g * DI;
  const float* zr = zs + (size_t)g * DI;
  float* tr = t + (size_t)g * DI;

  const float v0 = ya[lane]       + yb[lane];
  const float v1 = ya[lane + 64]  + yb[lane + 64];
  const float v2 = ya[lane + 128] + yb[lane + 128];
  float s1 = v0 + v1 + v2;
  float s2 = v0 * v0 + v1 * v1 + v2 * v2;
#pragma unroll
  for (int off = 32; off > 0; off >>= 1){
    s1 += __shfl_xor(s1, off);
    s2 += __shfl_xor(s2, off);
  }
  const float mu  = s1 * (1.f / DI);
  const float var = s2 * (1.f / DI) - mu * mu;
  const float rs  = rsqrtf(var + 1e-5f);
  tr[lane]       = ((v0 - mu) * rs * wn[lane]       + bn[lane])       * zr[lane];
  tr[lane + 64]  = ((v1 - mu) * rs * wn[lane + 64]  + bn[lane + 64])  * zr[lane + 64];
  tr[lane + 128] = ((v2 - mu) * rs * wn[lane + 128] + bn[lane + 128]) * zr[lane + 128];
}

// ---------------------------------------------------------------- out_proj GEMM (32768x96x192)
__global__ __launch_bounds__(256) void k_outproj(
    const float* __restrict__ t, const float* __restrict__ Wo, float* __restrict__ out)
{
  __shared__ float xl[32][36];
  __shared__ float wl[96][33];
  const int g0  = blockIdx.x * 32;
  const int tid = threadIdx.x;
  const int jg  = tid & 31;    // j = jg + 32*i (i<3)
  const int pg  = tid >> 5;    // p = pg*4 + pp

  float acc[4][3];
#pragma unroll
  for (int a = 0; a < 4; ++a){ acc[a][0]=0.f; acc[a][1]=0.f; acc[a][2]=0.f; }

  for (int kc = 0; kc < DI; kc += 32){
    __syncthreads();
    for (int idx = tid; idx < 8 * 32; idx += 256){
      int q = idx & 7, p = idx >> 3;
      const float4 v = *(const float4*)&t[(size_t)(g0 + p) * DI + kc + q * 4];
      xl[q * 4 + 0][p] = v.x; xl[q * 4 + 1][p] = v.y;
      xl[q * 4 + 2][p] = v.z; xl[q * 4 + 3][p] = v.w;
    }
    for (int idx = tid; idx < 96 * 32; idx += 256){
      int kk = idx & 31, j = idx >> 5;
      wl[j][kk] = Wo[(size_t)j * DI + kc + kk];
    }
    __syncthreads();
#pragma unroll
    for (int kk = 0; kk < 32; ++kk){
      const float4 xv = *(const float4*)&xl[kk][pg * 4];
      const float w0 = wl[jg][kk], w1 = wl[jg + 32][kk], w2 = wl[jg + 64][kk];
      acc[0][0] = __builtin_fmaf(xv.x, w0, acc[0][0]);
      acc[0][1] = __builtin_fmaf(xv.x, w1, acc[0][1]);
      acc[0][2] = __builtin_fmaf(xv.x, w2, acc[0][2]);
      acc[1][0] = __builtin_fmaf(xv.y, w0, acc[1][0]);
      acc[1][1] = __builtin_fmaf(xv.y, w1, acc[1][1]);
      acc[1][2] = __builtin_fmaf(xv.y, w2, acc[1][2]);
      acc[2][0] = __builtin_fmaf(xv.z, w0, acc[2][0]);
      acc[2][1] = __builtin_fmaf(xv.z, w1, acc[2][1]);
      acc[2][2] = __builtin_fmaf(xv.z, w2, acc[2][2]);
      acc[3][0] = __builtin_fmaf(xv.w, w0, acc[3][0]);
      acc[3][1] = __builtin_fmaf(xv.w, w1, acc[3][1]);
      acc[3][2] = __builtin_fmaf(xv.w, w2, acc[3][2]);
    }
  }
#pragma unroll
  for (int pp = 0; pp < 4; ++pp){
    const int p = g0 + pg * 4 + pp;
    out[(size_t)p * DM + jg]      = acc[pp][0];
    out[(size_t)p * DM + jg + 32] = acc[pp][1];
    out[(size_t)p * DM + jg + 64] = acc[pp][2];
  }
}

// ---------------------------------------------------------------- launch
extern "C" void kernel_launch(void* const* d_in, const int* in_sizes, int n_in,
                              void* d_out, int out_size, void* d_ws, size_t ws_size,
                              hipStream_t stream)
{
  const float* x    = (const float*)d_in[0];
  const float* Wi   = (const float*)d_in[1];
  const float* cw   = (const float*)d_in[2];
  const float* cb   = (const float*)d_in[3];
  const float* Wp   = (const float*)d_in[4];
  const float* Wdt  = (const float*)d_in[5];
  const float* dtb  = (const float*)d_in[6];
  const float* Alog = (const float*)d_in[7];
  const float* DsP  = (const float*)d_in[8];
  const float* wn   = (const float*)d_in[9];
  const float* bn   = (const float*)d_in[10];
  const float* Wo   = (const float*)d_in[11];
  float* out = (float*)d_out;
  float* ws  = (float*)d_ws;

  constexpr size_t SZ_BLD = (size_t)BATCH * LL * DI;        // 6,291,456
  float* xa    = ws;                                        // reused as projP after conv
  float* projP = ws;                                        // B*K*L*40 = 5,242,880 <= SZ_BLD
  float* zs    = ws + SZ_BLD;
  float* xc    = ws + 2 * SZ_BLD;                           // reused as t after pass2
  float* tbuf  = xc;
  float* ShH0  = ws + 3 * SZ_BLD;                           // Sh then (in-place) H0
  float* Ssum  = ws + 4 * SZ_BLD;                           // 393,216
  float* yA    = ws + 4 * SZ_BLD + 393216;
  float* yB    = ws + 5 * SZ_BLD + 393216;

  k_inproj <<<(BATCH * LL) / 32, 256, 0, stream>>>(x, Wi, xa, zs);
  k_conv   <<<(BATCH * LL * 48) / 256, 256, 0, stream>>>(xa, cw, cb, xc);
  k_xproj  <<<BATCH * (LL / 64), 256, 0, stream>>>(xc, Wp, projP);
  k_pass1  <<<BATCH * KK * NC, 192, 0, stream>>>(projP, xc, Wdt, dtb, Alog, ShH0, Ssum);
  k_prefix <<<(32 * DI * NS) / 256, 256, 0, stream>>>(ShH0, Ssum, Alog);
  k_pass2  <<<BATCH * 2 * NC, 192, 0, stream>>>(projP, xc, Wdt, dtb, Alog, DsP, ShH0, yA, yB);
  k_mergeln<<<(BATCH * LL) / 4, 256, 0, stream>>>(yA, yB, zs, wn, bn, tbuf);
  k_outproj<<<(BATCH * LL) / 32, 256, 0, stream>>>(tbuf, Wo, out);
}